// Round 13
// baseline (253.313 us; speedup 1.0000x reference)
//
#include <hip/hip_runtime.h>
#include <math.h>

#define N_NODES 100000
#define F_INDIM 256
#define NB 391            // coarse buckets: dst>>8, ceil(100000/256)
#define BCAP 9216         // bucket capacity: mean 8192 edges + 11 sigma

// pack two f32 into bf16 pair (RNE), lo = a, hi = b
__device__ __forceinline__ unsigned bf16pack(float a, float b) {
  unsigned ua = __float_as_uint(a);
  ua += 0x7FFFu + ((ua >> 16) & 1u);
  unsigned ub = __float_as_uint(b);
  ub += 0x7FFFu + ((ub >> 16) & 1u);
  return (ub & 0xFFFF0000u) | (ua >> 16);
}
__device__ __forceinline__ float lo16(unsigned v) { return __uint_as_float(v << 16); }
__device__ __forceinline__ float hi16(unsigned v) { return __uint_as_float(v & 0xFFFF0000u); }

using bf16x8 = __attribute__((ext_vector_type(8))) short;
using f32x4  = __attribute__((ext_vector_type(4))) float;
using fv4    = __attribute__((ext_vector_type(4))) float;
typedef unsigned long long ull;

// ---------------------------------------------------------------------------
// Heterogeneous (blockIdx%5: 0,1=bin 2,3,4=MFMA-GEMM), 512 threads. (= R8 +
// reg-cached dst across bin rounds + NT loads on streamed inputs)
// ---------------------------------------------------------------------------
__global__ __launch_bounds__(512) void gemm_bin(
    const float* __restrict__ x,
    const float* __restrict__ Wz, const float* __restrict__ Wr, const float* __restrict__ Wh,
    unsigned* __restrict__ XWb,
    const int* __restrict__ ei, const float* __restrict__ w,
    int* __restrict__ bucketCursor, uint2* __restrict__ staged, int E) {
  __shared__ unsigned smem[12672];   // 50688 B, overlaid between roles
  const int t = threadIdx.x;
  const int m = blockIdx.x % 5;
  if (m < 2) {
    // ---- binning role ----
    int* lc    = (int*)smem;          // [NB] counts / rank cursors
    int* lbase = (int*)smem + 512;    // [NB] reserved base within bucket
    if (t < NB) lc[t] = 0;
    __syncthreads();
    const int bid = (blockIdx.x / 5) * 2 + m;
    const int base = bid * 6144;
    int dstv[12];
#pragma unroll
    for (int i = 0; i < 12; i++) {
      int e = base + i * 512 + t;
      dstv[i] = (e < E) ? __builtin_nontemporal_load(ei + E + e) : -1;
      if (dstv[i] >= 0) atomicAdd(&lc[((unsigned)dstv[i]) >> 8], 1);
    }
    __syncthreads();
    if (t < NB) {
      int c = lc[t];
      lbase[t] = c ? atomicAdd(&bucketCursor[t], c) : 0;
    }
    __syncthreads();
    if (t < NB) lc[t] = 0;
    __syncthreads();
#pragma unroll
    for (int i = 0; i < 12; i++) {
      int e = base + i * 512 + t;
      if (dstv[i] >= 0) {
        unsigned dst = (unsigned)dstv[i];
        int b = dst >> 8;
        int r = lbase[b] + atomicAdd(&lc[b], 1);
        unsigned sv = (unsigned)__builtin_nontemporal_load(ei + e);
        float wv = __builtin_nontemporal_load(w + e);
        if (r < BCAP)
          staged[(size_t)b * BCAP + r] =
              make_uint2(sv | ((dst & 255u) << 17), __float_as_uint(wv));
      }
    }
    return;
  }
  // ---- MFMA GEMM role ----
  const int gid = (blockIdx.x / 5) * 3 + (m - 2);
  const int row0 = gid * 128;
  if (row0 >= N_NODES) return;
  ushort* sWt = (ushort*)smem;       // [96][264] bf16, col-major W (transposed)
  {
    const float* Ws[3] = {Wz, Wr, Wh};
#pragma unroll
    for (int mm = 0; mm < 3; mm++) {
      const float* Wp = Ws[mm];
      for (int i = t; i < 8192; i += 512) {
        int k = i >> 5, c = i & 31;
        unsigned uv = __float_as_uint(Wp[i]);
        uv += 0x7FFFu + ((uv >> 16) & 1u);
        sWt[(mm * 32 + c) * 264 + k] = (ushort)(uv >> 16);
      }
    }
  }
  __syncthreads();
  const int wv = t >> 6;       // wave 0..7
  const int l = t & 63;
  const int nl = l & 15;       // fragment row (A) / col (B,D)
  const int kg = l >> 4;       // k-group 0..3
  int arow = row0 + wv * 16 + nl;
  int arowc = arow < N_NODES ? arow : N_NODES - 1;
  f32x4 acc[6];
#pragma unroll
  for (int c = 0; c < 6; c++) acc[c] = (f32x4){0.f, 0.f, 0.f, 0.f};
  const float* xrow = x + (size_t)arowc * F_INDIM + kg * 8;
#pragma unroll
  for (int ks = 0; ks < 8; ks++) {
    fv4 xa = __builtin_nontemporal_load((const fv4*)(xrow + ks * 32));
    fv4 xb = __builtin_nontemporal_load((const fv4*)(xrow + ks * 32 + 4));
    uint4 au;
    au.x = bf16pack(xa[0], xa[1]);
    au.y = bf16pack(xa[2], xa[3]);
    au.z = bf16pack(xb[0], xb[1]);
    au.w = bf16pack(xb[2], xb[3]);
    bf16x8 af = *(bf16x8*)&au;
#pragma unroll
    for (int c = 0; c < 6; c++) {
      const ushort* bp = sWt + (c * 16 + nl) * 264 + ks * 32 + kg * 8;
      bf16x8 bf = *(const bf16x8*)bp;
      acc[c] = __builtin_amdgcn_mfma_f32_16x16x32_bf16(af, bf, acc[c], 0, 0, 0);
    }
  }
#pragma unroll
  for (int c = 0; c < 6; c++) {
#pragma unroll
    for (int r = 0; r < 4; r++) {
      float v = acc[c][r];
      float o = __shfl_xor(v, 1);
      int orow = row0 + wv * 16 + kg * 4 + r;
      if ((nl & 1) == 0 && orow < N_NODES)
        XWb[(size_t)orow * 48 + c * 8 + (nl >> 1)] = bf16pack(v, o);
    }
  }
}

// ---------------------------------------------------------------------------
// Per-bucket finalize, standalone, 512 threads (R12 variant): LDS fine
// histogram + deg accumulation, LDS scan -> rowstart/cnt/dis, cursor round
// permutes staged -> e2.
// ---------------------------------------------------------------------------
__global__ __launch_bounds__(512) void finalize(
    const uint2* __restrict__ staged, const int* __restrict__ bucketCursor,
    uint2* __restrict__ e2, int* __restrict__ rowstart, int* __restrict__ cntA,
    float* __restrict__ dis) {
  __shared__ int fc[256];
  __shared__ float fd[256];
  __shared__ int fscan[256];
  __shared__ int fcur[256];
  const int t = threadIdx.x;
  const int b = blockIdx.x;
  const size_t lo = (size_t)b * BCAP;
  int M = bucketCursor[b]; if (M > BCAP) M = BCAP;
  if (t < 256) { fc[t] = 0; fd[t] = 0.f; }
  __syncthreads();
  for (int i = t; i < M; i += 512) {
    uint2 ed = staged[lo + i];
    int fl = (ed.x >> 17) & 255;
    atomicAdd(&fc[fl], 1);
    atomicAdd(&fd[fl], __uint_as_float(ed.y));
  }
  __syncthreads();
  int v = (t < 256) ? fc[t] : 0;
  if (t < 256) fscan[t] = v;
  __syncthreads();
  for (int off = 1; off < 256; off <<= 1) {
    int xv = (t >= off && t < 256) ? fscan[t - off] : 0;
    __syncthreads();
    if (t < 256) fscan[t] += xv;
    __syncthreads();
  }
  if (t < 256) {
    int excl = fscan[t] - v;
    int node = (b << 8) + t;
    if (node < N_NODES) {
      rowstart[node] = (int)lo + excl;
      cntA[node] = v;
      dis[node] = rsqrtf(fd[t] + 1.0f);
    }
    fcur[t] = excl;
  }
  __syncthreads();
  for (int i = t; i < M; i += 512) {
    uint2 ed = staged[lo + i];
    int fl = (ed.x >> 17) & 255;
    int p = atomicAdd(&fcur[fl], 1);
    e2[lo + p] = make_uint2(ed.x & 0x1FFFFu, ed.y);
  }
}

// ---------------------------------------------------------------------------
// Fused gather + GRU + head — EXACT R8 structure + NT on streaming accesses
// (e2, Hp loads; outH, outY stores) so XWb keeps more L2 residency.
// ---------------------------------------------------------------------------
#define FMA8(vv, nn)                                              \
  a0 = fmaf(nn, lo16(vv.x), a0); a1 = fmaf(nn, hi16(vv.x), a1);   \
  a2 = fmaf(nn, lo16(vv.y), a2); a3 = fmaf(nn, hi16(vv.y), a3);   \
  a4 = fmaf(nn, lo16(vv.z), a4); a5 = fmaf(nn, hi16(vv.z), a5);   \
  a6 = fmaf(nn, lo16(vv.w), a6); a7 = fmaf(nn, hi16(vv.w), a7);

__global__ __launch_bounds__(256, 6) void gru_gather(
    const uint2* __restrict__ e2, const int* __restrict__ rowstart,
    const int* __restrict__ cnt, const unsigned* __restrict__ XWb,
    const float* __restrict__ dis, const float* __restrict__ Hp,
    const float* __restrict__ bz, const float* __restrict__ br, const float* __restrict__ bh,
    const float* __restrict__ LzW, const float* __restrict__ Lzb,
    const float* __restrict__ LrW, const float* __restrict__ Lrb,
    const float* __restrict__ LhW, const float* __restrict__ Lhb,
    const float* __restrict__ hW, const float* __restrict__ hb,
    float* __restrict__ outY, float* __restrict__ outH, int N) {
  __shared__ unsigned sLz[1024], sLr[1024], sLh[1024];   // bf16-pair packed, 12 KB
  __shared__ float aggTmp[4][5][96];
  __shared__ float sb96[96];
  __shared__ float sLzb[32], sLrb[32], sLhb[32], shW[32];
  __shared__ float2 sg2[4][48];
  __shared__ float shp[4][32], shr[4][32];
  __shared__ float shb;
  const int t = threadIdx.x;
  for (int i = t; i < 1024; i += 256) {
    int jj = i & 31, k2 = i >> 5;
    sLz[i] = bf16pack(LzW[(2 * k2) * 32 + jj], LzW[(2 * k2 + 1) * 32 + jj]);
    sLr[i] = bf16pack(LrW[(2 * k2) * 32 + jj], LrW[(2 * k2 + 1) * 32 + jj]);
    sLh[i] = bf16pack(LhW[(2 * k2) * 32 + jj], LhW[(2 * k2 + 1) * 32 + jj]);
  }
  if (t < 32) {
    sb96[t] = bz[t]; sb96[32 + t] = br[t]; sb96[64 + t] = bh[t];
    sLzb[t] = Lzb[t]; sLrb[t] = Lrb[t]; sLhb[t] = Lhb[t]; shW[t] = hW[t];
  }
  if (t == 0) shb = hb[0];
  __syncthreads();
  const int ws = t >> 6;
  const int l = t & 63;
  const int lp = (l < 48) ? l : 47;
  const int j = l & 31;
  const int half = l >> 5;
  const int sl = (l < 60) ? (l / 12) : 4;
  const int q  = (l < 60) ? (l % 12) : 11;
  const float* sgf = (const float*)&sg2[ws][0];
  int wid = blockIdx.x * 4 + ws;
  int nw = gridDim.x * 4;
  for (int n = wid; n < N; n += nw) {
    const int start = rowstart[n];
    const int c = cnt[n];
    const float d = dis[n];
    float a0 = 0.f, a1 = 0.f, a2 = 0.f, a3 = 0.f;
    float a4 = 0.f, a5 = 0.f, a6 = 0.f, a7 = 0.f;
    for (int e0 = 0; e0 < c; e0 += 60) {
      int srcv = 0; float pw = 0.f;
      if (l < 60 && e0 + l < c) {
        ull edv = __builtin_nontemporal_load((const ull*)&e2[start + e0 + l]);
        srcv = (int)(unsigned)(edv & 0xFFFFFFFFu);
        pw = __uint_as_float((unsigned)(edv >> 32)) * dis[srcv];   // w * dis[src]
      }
      int mm = c - e0; if (mm > 60) mm = 60;
      for (int k0 = 0; k0 < mm; k0 += 10) {          // 2 macro-iters: 10 edges
        int iA = k0 + sl, iB = k0 + 5 + sl;
        int sA = __shfl(srcv, iA), sB = __shfl(srcv, iB);
        float nA = __shfl(pw, iA), nB = __shfl(pw, iB);
        uint4 vA = *(const uint4*)(XWb + (size_t)sA * 48 + (q << 2));
        uint4 vB = *(const uint4*)(XWb + (size_t)sB * 48 + (q << 2));
        FMA8(vA, nA);
        FMA8(vB, nB);
      }
    }
    if (l < 60) {
      float4* dst4 = (float4*)&aggTmp[ws][sl][q * 8];
      dst4[0] = make_float4(a0, a1, a2, a3);
      dst4[1] = make_float4(a4, a5, a6, a7);
    }
    float g0 = 0.f, g1 = 0.f;
#pragma unroll
    for (int ss = 0; ss < 5; ss++) {
      float2 v2 = *(const float2*)&aggTmp[ws][ss][2 * lp];
      g0 += v2.x; g1 += v2.y;
    }
    g0 *= d; g1 *= d;
    {   // self-loop + bias
      unsigned v = XWb[(size_t)n * 48 + lp];
      float d2 = d * d;
      g0 = fmaf(d2, lo16(v), g0) + sb96[2 * lp];
      g1 = fmaf(d2, hi16(v), g1) + sb96[2 * lp + 1];
    }
    if (l < 48) sg2[ws][l] = make_float2(g0, g1);
    float hpj = 0.f;
    if (l < 32) {
      hpj = __builtin_nontemporal_load(&Hp[(size_t)n * 32 + l]);
      shp[ws][l] = hpj;
    }
    const unsigned* Wm = half ? sLr : sLz;
    const float* gsel = half ? (sgf + 32) : sgf;
    float val = half ? sLrb[j] : sLzb[j];
#pragma unroll
    for (int k2 = 0; k2 < 16; k2++) {
      unsigned wv = Wm[k2 * 32 + j];
      val = fmaf(gsel[2 * k2],     lo16(wv), val);
      val = fmaf(gsel[2 * k2 + 1], hi16(wv), val);
    }
#pragma unroll
    for (int k2 = 16; k2 < 32; k2++) {
      unsigned wv = Wm[k2 * 32 + j];
      val = fmaf(shp[ws][2 * k2 - 32], lo16(wv), val);
      val = fmaf(shp[ws][2 * k2 - 31], hi16(wv), val);
    }
    float gate = 1.f / (1.f + __expf(-val));
    if (half) shr[ws][j] = shp[ws][j] * gate;
    float s = half ? 0.f : sLhb[j];
#pragma unroll
    for (int k2 = 0; k2 < 16; k2++) {
      int kk2 = half ? (k2 + 16) : k2;
      unsigned wv = sLh[kk2 * 32 + j];
      float x0 = half ? shr[ws][2 * k2]     : sgf[64 + 2 * k2];
      float x1 = half ? shr[ws][2 * k2 + 1] : sgf[64 + 2 * k2 + 1];
      s = fmaf(x0, lo16(wv), s);
      s = fmaf(x1, hi16(wv), s);
    }
    s += __shfl_xor(s, 32);
    if (!half) {
      float ht = tanhf(s);
      float h = gate * hpj + (1.f - gate) * ht;
      __builtin_nontemporal_store(h, &outH[(size_t)n * 32 + j]);
      float cacc = fmaxf(h, 0.f) * shW[j];
#pragma unroll
      for (int off = 16; off > 0; off >>= 1) cacc += __shfl_xor(cacc, off, 32);
      if (j == 0) __builtin_nontemporal_store(cacc + shb, &outY[n]);
    }
  }
}

// ---------------------------------------------------------------------------
extern "C" void kernel_launch(void* const* d_in, const int* in_sizes, int n_in,
                              void* d_out, int out_size, void* d_ws, size_t ws_size,
                              hipStream_t stream) {
  const float* x    = (const float*)d_in[0];
  const int*   ei   = (const int*)d_in[1];
  const float* w    = (const float*)d_in[2];
  const float* Hp   = (const float*)d_in[3];
  const float* Wz   = (const float*)d_in[4];
  const float* bz   = (const float*)d_in[5];
  const float* Wr   = (const float*)d_in[6];
  const float* br   = (const float*)d_in[7];
  const float* Wh   = (const float*)d_in[8];
  const float* bh   = (const float*)d_in[9];
  const float* LzW  = (const float*)d_in[10];
  const float* Lzb  = (const float*)d_in[11];
  const float* LrW  = (const float*)d_in[12];
  const float* Lrb  = (const float*)d_in[13];
  const float* LhW  = (const float*)d_in[14];
  const float* Lhb  = (const float*)d_in[15];
  const float* hW   = (const float*)d_in[16];
  const float* hb   = (const float*)d_in[17];

  const int N = N_NODES;
  const int E = in_sizes[2];

  char* p = (char*)d_ws;
  unsigned* XWb   = (unsigned*)p;  p += (size_t)(N * 48 + 64) * 4;     // 19.2 MB
  uint2*    staged= (uint2*)p;     p += (size_t)NB * BCAP * 8;         // 28.8 MB
  uint2*    e2    = (uint2*)p;     p += (size_t)NB * BCAP * 8;         // 28.8 MB
  int* rowstart   = (int*)p;       p += (size_t)N * 4;
  int* cnt        = (int*)p;       p += (size_t)N * 4;
  float* dis      = (float*)p;     p += (size_t)N * 4;
  int* bucketCursor = (int*)p;     p += (NB + 1) * 4;

  float* outY = (float*)d_out;           // N
  float* outH = outY + N;                // N*32

  hipMemsetAsync(bucketCursor, 0, (NB + 1) * sizeof(int), stream);

  // 261 groups of 5: 522 bin blocks, 783 gemm blocks (last gemm tile guarded)
  gemm_bin<<<1305, 512, 0, stream>>>(x, Wz, Wr, Wh, XWb, ei, w,
                                     bucketCursor, staged, E);
  finalize<<<NB, 512, 0, stream>>>(staged, bucketCursor, e2, rowstart, cnt, dis);
  gru_gather<<<1536, 256, 0, stream>>>(e2, rowstart, cnt, XWb, dis, Hp,
                                       bz, br, bh,
                                       LzW, Lzb, LrW, Lrb, LhW, Lhb,
                                       hW, hb, outY, outH, N);
}

// Round 14
// 244.505 us; speedup vs baseline: 1.0360x; 1.0360x over previous
//
#include <hip/hip_runtime.h>
#include <math.h>

#define N_NODES 100000
#define F_INDIM 256
#define NB 391            // coarse buckets: dst>>8, ceil(100000/256)
#define BCAP 9216         // bucket capacity: mean 8192 edges + 11 sigma

// pack two f32 into bf16 pair (RNE), lo = a, hi = b
__device__ __forceinline__ unsigned bf16pack(float a, float b) {
  unsigned ua = __float_as_uint(a);
  ua += 0x7FFFu + ((ua >> 16) & 1u);
  unsigned ub = __float_as_uint(b);
  ub += 0x7FFFu + ((ub >> 16) & 1u);
  return (ub & 0xFFFF0000u) | (ua >> 16);
}
__device__ __forceinline__ float lo16(unsigned v) { return __uint_as_float(v << 16); }
__device__ __forceinline__ float hi16(unsigned v) { return __uint_as_float(v & 0xFFFF0000u); }

using bf16x8 = __attribute__((ext_vector_type(8))) short;
using f32x4  = __attribute__((ext_vector_type(4))) float;

// ---------------------------------------------------------------------------
// Heterogeneous (blockIdx%5: 0,1=bin 2,3,4=MFMA-GEMM), 512 threads. (= R8)
// ---------------------------------------------------------------------------
__global__ __launch_bounds__(512) void gemm_bin(
    const float* __restrict__ x,
    const float* __restrict__ Wz, const float* __restrict__ Wr, const float* __restrict__ Wh,
    unsigned* __restrict__ XWb,
    const int* __restrict__ ei, const float* __restrict__ w,
    int* __restrict__ bucketCursor, uint2* __restrict__ staged, int E) {
  __shared__ unsigned smem[12672];   // 50688 B, overlaid between roles
  const int t = threadIdx.x;
  const int m = blockIdx.x % 5;
  if (m < 2) {
    // ---- binning role ----
    int* lc    = (int*)smem;          // [NB] counts / rank cursors
    int* lbase = (int*)smem + 512;    // [NB] reserved base within bucket
    if (t < NB) lc[t] = 0;
    __syncthreads();
    const int bid = (blockIdx.x / 5) * 2 + m;
    const int base = bid * 6144;
#pragma unroll
    for (int i = 0; i < 12; i++) {
      int e = base + i * 512 + t;
      if (e < E) atomicAdd(&lc[((unsigned)ei[E + e]) >> 8], 1);
    }
    __syncthreads();
    if (t < NB) {
      int c = lc[t];
      lbase[t] = c ? atomicAdd(&bucketCursor[t], c) : 0;
    }
    __syncthreads();
    if (t < NB) lc[t] = 0;
    __syncthreads();
#pragma unroll
    for (int i = 0; i < 12; i++) {
      int e = base + i * 512 + t;
      if (e < E) {
        unsigned dst = (unsigned)ei[E + e];
        int b = dst >> 8;
        int r = lbase[b] + atomicAdd(&lc[b], 1);
        if (r < BCAP)
          staged[(size_t)b * BCAP + r] =
              make_uint2((unsigned)ei[e] | ((dst & 255u) << 17), __float_as_uint(w[e]));
      }
    }
    return;
  }
  // ---- MFMA GEMM role ----
  const int gid = (blockIdx.x / 5) * 3 + (m - 2);
  const int row0 = gid * 128;
  if (row0 >= N_NODES) return;
  ushort* sWt = (ushort*)smem;       // [96][264] bf16, col-major W (transposed)
  {
    const float* Ws[3] = {Wz, Wr, Wh};
#pragma unroll
    for (int mm = 0; mm < 3; mm++) {
      const float* Wp = Ws[mm];
      for (int i = t; i < 8192; i += 512) {
        int k = i >> 5, c = i & 31;
        unsigned uv = __float_as_uint(Wp[i]);
        uv += 0x7FFFu + ((uv >> 16) & 1u);
        sWt[(mm * 32 + c) * 264 + k] = (ushort)(uv >> 16);
      }
    }
  }
  __syncthreads();
  const int wv = t >> 6;       // wave 0..7
  const int l = t & 63;
  const int nl = l & 15;       // fragment row (A) / col (B,D)
  const int kg = l >> 4;       // k-group 0..3
  int arow = row0 + wv * 16 + nl;
  int arowc = arow < N_NODES ? arow : N_NODES - 1;
  f32x4 acc[6];
#pragma unroll
  for (int c = 0; c < 6; c++) acc[c] = (f32x4){0.f, 0.f, 0.f, 0.f};
  const float* xrow = x + (size_t)arowc * F_INDIM + kg * 8;
#pragma unroll
  for (int ks = 0; ks < 8; ks++) {
    float4 xa = *(const float4*)(xrow + ks * 32);
    float4 xb = *(const float4*)(xrow + ks * 32 + 4);
    uint4 au;
    au.x = bf16pack(xa.x, xa.y);
    au.y = bf16pack(xa.z, xa.w);
    au.z = bf16pack(xb.x, xb.y);
    au.w = bf16pack(xb.z, xb.w);
    bf16x8 af = *(bf16x8*)&au;
#pragma unroll
    for (int c = 0; c < 6; c++) {
      const ushort* bp = sWt + (c * 16 + nl) * 264 + ks * 32 + kg * 8;
      bf16x8 bf = *(const bf16x8*)bp;
      acc[c] = __builtin_amdgcn_mfma_f32_16x16x32_bf16(af, bf, acc[c], 0, 0, 0);
    }
  }
#pragma unroll
  for (int c = 0; c < 6; c++) {
#pragma unroll
    for (int r = 0; r < 4; r++) {
      float v = acc[c][r];
      float o = __shfl_xor(v, 1);
      int orow = row0 + wv * 16 + kg * 4 + r;
      if ((nl & 1) == 0 && orow < N_NODES)
        XWb[(size_t)orow * 48 + c * 8 + (nl >> 1)] = bf16pack(v, o);
    }
  }
}

// ---------------------------------------------------------------------------
// Per-bucket finalize (one block per coarse bucket): LDS fine histogram +
// deg accumulation, LDS scan -> rowstart/cnt/dis, cursor round -> e2. (= R8)
// ---------------------------------------------------------------------------
__global__ __launch_bounds__(256) void finalize(
    const uint2* __restrict__ staged, const int* __restrict__ bucketCursor,
    uint2* __restrict__ e2, int* __restrict__ rowstart, int* __restrict__ cntA,
    float* __restrict__ dis) {
  __shared__ int fc[256];
  __shared__ float fd[256];
  __shared__ int fscan[256];
  __shared__ int fcur[256];
  const int t = threadIdx.x;
  const int b = blockIdx.x;
  const size_t lo = (size_t)b * BCAP;
  int M = bucketCursor[b]; if (M > BCAP) M = BCAP;
  fc[t] = 0; fd[t] = 0.f;
  __syncthreads();
  for (int i = t; i < M; i += 256) {
    uint2 ed = staged[lo + i];
    int fl = (ed.x >> 17) & 255;
    atomicAdd(&fc[fl], 1);
    atomicAdd(&fd[fl], __uint_as_float(ed.y));
  }
  __syncthreads();
  int v = fc[t];
  fscan[t] = v;
  __syncthreads();
  for (int off = 1; off < 256; off <<= 1) {
    int xv = (t >= off) ? fscan[t - off] : 0;
    __syncthreads();
    fscan[t] += xv;
    __syncthreads();
  }
  int excl = fscan[t] - v;
  int node = (b << 8) + t;
  if (node < N_NODES) {
    rowstart[node] = (int)lo + excl;
    cntA[node] = v;
    dis[node] = rsqrtf(fd[t] + 1.0f);
  }
  fcur[t] = excl;
  __syncthreads();
  for (int i = t; i < M; i += 256) {
    uint2 ed = staged[lo + i];
    int fl = (ed.x >> 17) & 255;
    int p = atomicAdd(&fcur[fl], 1);
    e2[lo + p] = make_uint2(ed.x & 0x1FFFFu, ed.y);
  }
}

// ---------------------------------------------------------------------------
// Fused gather + GRU + head — EXACT R8 structure (best measured).
// One wave64 per node; 5 edges per wave-load (slot s=l/12, quarter q=l%12,
// dwordx4 per lane); 2 macro-iters per 60-edge chunk (2 loads in flight).
// ---------------------------------------------------------------------------
#define FMA8(vv, nn)                                              \
  a0 = fmaf(nn, lo16(vv.x), a0); a1 = fmaf(nn, hi16(vv.x), a1);   \
  a2 = fmaf(nn, lo16(vv.y), a2); a3 = fmaf(nn, hi16(vv.y), a3);   \
  a4 = fmaf(nn, lo16(vv.z), a4); a5 = fmaf(nn, hi16(vv.z), a5);   \
  a6 = fmaf(nn, lo16(vv.w), a6); a7 = fmaf(nn, hi16(vv.w), a7);

__global__ __launch_bounds__(256, 6) void gru_gather(
    const uint2* __restrict__ e2, const int* __restrict__ rowstart,
    const int* __restrict__ cnt, const unsigned* __restrict__ XWb,
    const float* __restrict__ dis, const float* __restrict__ Hp,
    const float* __restrict__ bz, const float* __restrict__ br, const float* __restrict__ bh,
    const float* __restrict__ LzW, const float* __restrict__ Lzb,
    const float* __restrict__ LrW, const float* __restrict__ Lrb,
    const float* __restrict__ LhW, const float* __restrict__ Lhb,
    const float* __restrict__ hW, const float* __restrict__ hb,
    float* __restrict__ outY, float* __restrict__ outH, int N) {
  __shared__ unsigned sLz[1024], sLr[1024], sLh[1024];   // bf16-pair packed, 12 KB
  __shared__ float aggTmp[4][5][96];
  __shared__ float sb96[96];
  __shared__ float sLzb[32], sLrb[32], sLhb[32], shW[32];
  __shared__ float2 sg2[4][48];
  __shared__ float shp[4][32], shr[4][32];
  __shared__ float shb;
  const int t = threadIdx.x;
  for (int i = t; i < 1024; i += 256) {
    int jj = i & 31, k2 = i >> 5;
    sLz[i] = bf16pack(LzW[(2 * k2) * 32 + jj], LzW[(2 * k2 + 1) * 32 + jj]);
    sLr[i] = bf16pack(LrW[(2 * k2) * 32 + jj], LrW[(2 * k2 + 1) * 32 + jj]);
    sLh[i] = bf16pack(LhW[(2 * k2) * 32 + jj], LhW[(2 * k2 + 1) * 32 + jj]);
  }
  if (t < 32) {
    sb96[t] = bz[t]; sb96[32 + t] = br[t]; sb96[64 + t] = bh[t];
    sLzb[t] = Lzb[t]; sLrb[t] = Lrb[t]; sLhb[t] = Lhb[t]; shW[t] = hW[t];
  }
  if (t == 0) shb = hb[0];
  __syncthreads();
  const int ws = t >> 6;
  const int l = t & 63;
  const int lp = (l < 48) ? l : 47;
  const int j = l & 31;
  const int half = l >> 5;
  const int sl = (l < 60) ? (l / 12) : 4;
  const int q  = (l < 60) ? (l % 12) : 11;
  const float* sgf = (const float*)&sg2[ws][0];
  int wid = blockIdx.x * 4 + ws;
  int nw = gridDim.x * 4;
  for (int n = wid; n < N; n += nw) {
    const int start = rowstart[n];
    const int c = cnt[n];
    const float d = dis[n];
    float a0 = 0.f, a1 = 0.f, a2 = 0.f, a3 = 0.f;
    float a4 = 0.f, a5 = 0.f, a6 = 0.f, a7 = 0.f;
    for (int e0 = 0; e0 < c; e0 += 60) {
      int srcv = 0; float pw = 0.f;
      if (l < 60 && e0 + l < c) {
        uint2 ed = e2[start + e0 + l];
        srcv = (int)ed.x;
        pw = __uint_as_float(ed.y) * dis[srcv];      // w * dis[src]
      }
      int mm = c - e0; if (mm > 60) mm = 60;
      for (int k0 = 0; k0 < mm; k0 += 10) {          // 2 macro-iters: 10 edges
        int iA = k0 + sl, iB = k0 + 5 + sl;
        int sA = __shfl(srcv, iA), sB = __shfl(srcv, iB);
        float nA = __shfl(pw, iA), nB = __shfl(pw, iB);
        uint4 vA = *(const uint4*)(XWb + (size_t)sA * 48 + (q << 2));
        uint4 vB = *(const uint4*)(XWb + (size_t)sB * 48 + (q << 2));
        FMA8(vA, nA);
        FMA8(vB, nB);
      }
    }
    if (l < 60) {
      float4* dst4 = (float4*)&aggTmp[ws][sl][q * 8];
      dst4[0] = make_float4(a0, a1, a2, a3);
      dst4[1] = make_float4(a4, a5, a6, a7);
    }
    float g0 = 0.f, g1 = 0.f;
#pragma unroll
    for (int ss = 0; ss < 5; ss++) {
      float2 v2 = *(const float2*)&aggTmp[ws][ss][2 * lp];
      g0 += v2.x; g1 += v2.y;
    }
    g0 *= d; g1 *= d;
    {   // self-loop + bias
      unsigned v = XWb[(size_t)n * 48 + lp];
      float d2 = d * d;
      g0 = fmaf(d2, lo16(v), g0) + sb96[2 * lp];
      g1 = fmaf(d2, hi16(v), g1) + sb96[2 * lp + 1];
    }
    if (l < 48) sg2[ws][l] = make_float2(g0, g1);
    float hpj = 0.f;
    if (l < 32) { hpj = Hp[(size_t)n * 32 + l]; shp[ws][l] = hpj; }
    const unsigned* Wm = half ? sLr : sLz;
    const float* gsel = half ? (sgf + 32) : sgf;
    float val = half ? sLrb[j] : sLzb[j];
#pragma unroll
    for (int k2 = 0; k2 < 16; k2++) {
      unsigned wv = Wm[k2 * 32 + j];
      val = fmaf(gsel[2 * k2],     lo16(wv), val);
      val = fmaf(gsel[2 * k2 + 1], hi16(wv), val);
    }
#pragma unroll
    for (int k2 = 16; k2 < 32; k2++) {
      unsigned wv = Wm[k2 * 32 + j];
      val = fmaf(shp[ws][2 * k2 - 32], lo16(wv), val);
      val = fmaf(shp[ws][2 * k2 - 31], hi16(wv), val);
    }
    float gate = 1.f / (1.f + __expf(-val));
    if (half) shr[ws][j] = shp[ws][j] * gate;
    float s = half ? 0.f : sLhb[j];
#pragma unroll
    for (int k2 = 0; k2 < 16; k2++) {
      int kk2 = half ? (k2 + 16) : k2;
      unsigned wv = sLh[kk2 * 32 + j];
      float x0 = half ? shr[ws][2 * k2]     : sgf[64 + 2 * k2];
      float x1 = half ? shr[ws][2 * k2 + 1] : sgf[64 + 2 * k2 + 1];
      s = fmaf(x0, lo16(wv), s);
      s = fmaf(x1, hi16(wv), s);
    }
    s += __shfl_xor(s, 32);
    if (!half) {
      float ht = tanhf(s);
      float h = gate * hpj + (1.f - gate) * ht;
      outH[(size_t)n * 32 + j] = h;
      float cacc = fmaxf(h, 0.f) * shW[j];
#pragma unroll
      for (int off = 16; off > 0; off >>= 1) cacc += __shfl_xor(cacc, off, 32);
      if (j == 0) outY[n] = cacc + shb;
    }
  }
}

// ---------------------------------------------------------------------------
extern "C" void kernel_launch(void* const* d_in, const int* in_sizes, int n_in,
                              void* d_out, int out_size, void* d_ws, size_t ws_size,
                              hipStream_t stream) {
  const float* x    = (const float*)d_in[0];
  const int*   ei   = (const int*)d_in[1];
  const float* w    = (const float*)d_in[2];
  const float* Hp   = (const float*)d_in[3];
  const float* Wz   = (const float*)d_in[4];
  const float* bz   = (const float*)d_in[5];
  const float* Wr   = (const float*)d_in[6];
  const float* br   = (const float*)d_in[7];
  const float* Wh   = (const float*)d_in[8];
  const float* bh   = (const float*)d_in[9];
  const float* LzW  = (const float*)d_in[10];
  const float* Lzb  = (const float*)d_in[11];
  const float* LrW  = (const float*)d_in[12];
  const float* Lrb  = (const float*)d_in[13];
  const float* LhW  = (const float*)d_in[14];
  const float* Lhb  = (const float*)d_in[15];
  const float* hW   = (const float*)d_in[16];
  const float* hb   = (const float*)d_in[17];

  const int N = N_NODES;
  const int E = in_sizes[2];

  char* p = (char*)d_ws;
  unsigned* XWb   = (unsigned*)p;  p += (size_t)(N * 48 + 64) * 4;     // 19.2 MB
  uint2*    staged= (uint2*)p;     p += (size_t)NB * BCAP * 8;         // 28.8 MB
  uint2*    e2    = (uint2*)p;     p += (size_t)NB * BCAP * 8;         // 28.8 MB
  int* rowstart   = (int*)p;       p += (size_t)N * 4;
  int* cnt        = (int*)p;       p += (size_t)N * 4;
  float* dis      = (float*)p;     p += (size_t)N * 4;
  int* bucketCursor = (int*)p;     p += (NB + 1) * 4;

  float* outY = (float*)d_out;           // N
  float* outH = outY + N;                // N*32

  hipMemsetAsync(bucketCursor, 0, (NB + 1) * sizeof(int), stream);

  // 261 groups of 5: 522 bin blocks, 783 gemm blocks (last gemm tile guarded)
  gemm_bin<<<1305, 512, 0, stream>>>(x, Wz, Wr, Wh, XWb, ei, w,
                                     bucketCursor, staged, E);
  finalize<<<NB, 256, 0, stream>>>(staged, bucketCursor, e2, rowstart, cnt, dis);
  gru_gather<<<1536, 256, 0, stream>>>(e2, rowstart, cnt, XWb, dis, Hp,
                                       bz, br, bh,
                                       LzW, Lzb, LrW, Lrb, LhW, Lhb,
                                       hW, hb, outY, outH, N);
}